// Round 5
// baseline (1803.636 us; speedup 1.0000x reference)
//
#include <hip/hip_runtime.h>
#include <cstddef>

#define LOG2E 1.4426950408889634f
#define LN2   0.6931471805599453f

typedef float    f32x2 __attribute__((ext_vector_type(2)));
typedef float    f32x4 __attribute__((ext_vector_type(4)));
typedef _Float16 half8 __attribute__((ext_vector_type(8)));

constexpr int K_    = 256;
constexpr int T_    = 2048;
constexpr int DMAX_ = 64;
constexpr int B_    = 16;

__device__ __forceinline__ float fexp2(float x) { return __builtin_amdgcn_exp2f(x); }
__device__ __forceinline__ float flog2(float x) { return __builtin_amdgcn_logf(x); }
__device__ __forceinline__ float frcp (float x) { return __builtin_amdgcn_rcpf(x); }

// cross-half (lane ^ 32) exchange via v_permlane32_swap_b32 (VALU).
// %1 early-clobber guarantees distinct regs; r.x+r.y = cross-half sum
// regardless of HW swap direction.
__device__ __forceinline__ f32x2 xchg32(float x) {
    float a = x, b;
    asm("v_mov_b32 %1, %2\n\t"
        "s_nop 1\n\t"
        "v_permlane32_swap_b32 %0, %1"
        : "+v"(a), "=&v"(b)
        : "v"(x));
    return (f32x2){a, b};
}

// 16-lane-row pair exchange via v_permlane16_swap_b32 (VALU). With both
// operands = x, {r.x + r.y} = sum over each adjacent 16-row pair under any
// of the plausible row-pairing conventions (same argument as xchg32).
__device__ __forceinline__ f32x2 xchg16(float x) {
    float a = x, b;
    asm("v_mov_b32 %1, %2\n\t"
        "s_nop 1\n\t"
        "v_permlane16_swap_b32 %0, %1"
        : "+v"(a), "=&v"(b)
        : "v"(x));
    return (f32x2){a, b};
}

__device__ __forceinline__ float bpermf(int addr, float v) {
    return __builtin_bit_cast(float,
        __builtin_amdgcn_ds_bpermute(addr, __builtin_bit_cast(int, v)));
}

// max-reduce across a 16-lane row via DPP row_ror (VALU, no LDS pipe).
template<int CTRL>
__device__ __forceinline__ float dpp_maxf(float x) {
    int m = __builtin_amdgcn_update_dpp(0, __builtin_bit_cast(int, x), CTRL, 0xF, 0xF, true);
    return fmaxf(x, __builtin_bit_cast(float, m));
}

// 1024 threads = 16 waves, 4 waves/SIMD (this round: 2x TLP for latency
// hiding of the barrier-correlated MFMA/LDS stall window).
// Wave w owns columns j = 16w + (lane&15). Quarter g = lane>>4 owns ages
// 16g+1..16g+16 as 8 pairs v[i] = {16g+1+i, 16g+9+i}.
//   -> MFMA d.x (col = lane&15) IS each lane's own column: no select.
//   -> S-reduce: pair-sum, permlane16_swap (+), permlane32_swap (+): all VALU.
//   -> age handoff across quarters: one ds_bpermute (pull from lane-16).
// Per-wave work halves (dot 8 pk_fma, shift 7 pk_mul, 8 MFMAs, Bf=32 VGPR).
// Anchor machinery at half rate (even: DPP max + lds_red[16] write; odd:
// read + reduce). One pinned barrier per step; depth-3 global prefetch ring.
__global__ __launch_bounds__(1024)
__attribute__((amdgpu_waves_per_eu(4, 4)))
void hsmm_fwd_kernel(const float* __restrict__ logB,   // [B,T,K]
                     const float* __restrict__ pi,     // [K]
                     const float* __restrict__ A,      // [K,K]
                     const float* __restrict__ D,      // [K,DMAX]
                     float* __restrict__ out)          // [16] loglik ++ [B,T,K] alphas
{
    const int b    = blockIdx.x;
    const int tid  = threadIdx.x;
    const int w    = tid >> 6;                 // wave 0..15
    const int lane = tid & 63;
    const int j    = (w << 4) | (lane & 15);   // column 0..255
    const int g    = lane >> 4;                // age quarter 0..3

    alignas(16) __shared__ _Float16 lds_ph[2][K_];    // p f16, ping-pong by t&1
    alignas(16) __shared__ float    lds_red[16];      // per-wave max a_in

    // ---- init: B-fragments (P = exp(A_logits), f16, MFMA B-layout) ----
    // wave w's N-tile = columns 16w..16w+15; lane holds B rows
    // k = kc*32 + g*8 + jj at column n0 = j.
    half8 Bf[8];
    {
        const int krow = g * 8;
        #pragma unroll
        for (int kc = 0; kc < 8; ++kc) {
            #pragma unroll
            for (int jj = 0; jj < 8; ++jj) {
                const int k = kc * 32 + krow + jj;
                Bf[kc][jj] = (_Float16)fexp2(A[(size_t)k * K_ + j] * LOG2E);
            }
        }
    }
    // pD pairs for quarter g: pDf[i] = {pD(age 16g+1+i), pD(age 16g+9+i)}
    f32x2 pDf[8];
    {
        const float* Dj = D + (size_t)j * DMAX_ + 16 * g;
        #pragma unroll
        for (int i = 0; i < 8; ++i)
            pDf[i] = (f32x2){ fexp2(Dj[i] * LOG2E), fexp2(Dj[8 + i] * LOG2E) };
    }

    // v[i] = values at ages {16g+1+i, 16g+9+i}
    f32x2 v[8];
    #pragma unroll
    for (int i = 0; i < 8; ++i) v[i] = (f32x2){0.0f, 0.0f};
    if (g == 0) v[0].x = 1.0f;          // age-1 holds pi mass (anchor = pi)
    float mcol     = pi[j] * LOG2E;     // column anchor (base-2)
    float cumb     = 0.0f;
    float m_anchor = 0.0f;              // block anchor (lag 2-3)

    const int bpa = ((lane - 16) & 63) << 2;   // bpermute: pull from lane-16

    if (tid < 16) lds_red[tid] = 0.0f;
    __syncthreads();

    const float* lb = logB + (size_t)b * T_ * K_ + j;
    float*       ao = out + 16 + (size_t)b * T_ * K_ + j;

    // depth-3 prefetch ring for the per-step emission
    float bld0 = lb[0];
    float bld1 = lb[K_];
    float bld2 = lb[2 * K_];
    int   ldoff = 3 * K_;
    int   aoff  = 0;

    // static even/odd step body (EVEN: anchor-feed write; ODD: anchor update)
    auto body = [&](int t, int s, bool even) __attribute__((always_inline)) {
        cumb = fmaf(bld0, LOG2E, cumb);

        const float argh = 0.5f * (cumb + mcol - m_anchor);
        const float ea   = fminf(fexp2(argh),  1.8e19f);
        const float ga   = fminf(fexp2(-argh), 1.8e19f);
        const float mac  = m_anchor - cumb;

        // ---- duration dot: 8 pk_fma + tree + permlane16 + permlane32 ----
        f32x2 s0 = {0.f,0.f}, s1 = {0.f,0.f}, s2 = {0.f,0.f}, s3 = {0.f,0.f};
        s0 = __builtin_elementwise_fma(v[0], pDf[0], s0);
        s1 = __builtin_elementwise_fma(v[1], pDf[1], s1);
        s2 = __builtin_elementwise_fma(v[2], pDf[2], s2);
        s3 = __builtin_elementwise_fma(v[3], pDf[3], s3);
        s0 = __builtin_elementwise_fma(v[4], pDf[4], s0);
        s1 = __builtin_elementwise_fma(v[5], pDf[5], s1);
        s2 = __builtin_elementwise_fma(v[6], pDf[6], s2);
        s3 = __builtin_elementwise_fma(v[7], pDf[7], s3);
        f32x2 sp = (s0 + s1) + (s2 + s3);
        float Sl = sp.x + sp.y;                 // own-quarter partial
        f32x2 q16 = xchg16(Sl);
        float Sq  = q16.x + q16.y;              // quarter-pair sum
        f32x2 pr  = xchg32(Sq);
        float S   = pr.x + pr.y;                // full sum over 4 quarters

        float p = fminf(S * ea * ea, 60000.0f); // f16-overflow clamp
        if (lane < 16) lds_ph[s][j] = (_Float16)p;

        // ---- the ONE barrier: pinned so no LDS op crosses it ----
        asm volatile("s_waitcnt lgkmcnt(0)" ::: "memory");
        __builtin_amdgcn_sched_barrier(0);
        __builtin_amdgcn_s_barrier();
        __builtin_amdgcn_sched_barrier(0);

        // globals: prefetch t+3 (in flight across barriers) + alpha store
        bld0 = bld1; bld1 = bld2;
        bld2 = lb[ldoff];
        ldoff += (ldoff < (T_ - 1) * K_) ? K_ : 0;
        if (lane < 16) ao[aoff] = (cumb + mcol + flog2(S)) * LN2;
        aoff += K_;

        f32x4 r0, r1, r2, r3;
        if (!even) {    // hoisted anchor read (latency overlaps MFMA)
            r0 = ((const f32x4*)lds_red)[0];
            r1 = ((const f32x4*)lds_red)[1];
            r2 = ((const f32x4*)lds_red)[2];
            r3 = ((const f32x4*)lds_red)[3];
        }

        // ---- MFMA matvec: 8 MFMAs, 2 independent 4-deep chains ----
        const _Float16* pb = lds_ph[s];
        const int fo = g * 8;
        const f32x4 z = {0.f,0.f,0.f,0.f};
        f32x4 d0a = z, d0b = z;
        #pragma unroll
        for (int kc = 0; kc < 4; ++kc) {
            half8 af = *(const half8*)(pb + kc * 32 + fo);
            d0a = __builtin_amdgcn_mfma_f32_16x16x32_f16(af, Bf[kc], d0a, 0, 0, 0);
        }
        #pragma unroll
        for (int kc = 4; kc < 8; ++kc) {
            half8 af = *(const half8*)(pb + kc * 32 + fo);
            d0b = __builtin_amdgcn_mfma_f32_16x16x32_f16(af, Bf[kc], d0b, 0, 0, 0);
        }
        float mySmv = d0a.x + d0b.x;            // own column directly

        float m_next = 0.0f;
        if (even) {
            // anchor feed: wave max over its 16 columns via DPP row_ror
            float mx = mySmv;
            mx = dpp_maxf<0x121>(mx);   // ror:1
            mx = dpp_maxf<0x122>(mx);   // ror:2
            mx = dpp_maxf<0x124>(mx);   // ror:4
            mx = dpp_maxf<0x128>(mx);   // ror:8
            if (lane == 0) lds_red[w] = m_anchor + flog2(fmaxf(mx, 1e-30f));
        } else {
            float m1 = fmaxf(fmaxf(r0.x, r0.y), fmaxf(r0.z, r0.w));
            float m2 = fmaxf(fmaxf(r1.x, r1.y), fmaxf(r1.z, r1.w));
            float m3 = fmaxf(fmaxf(r2.x, r2.y), fmaxf(r2.z, r2.w));
            float m4 = fmaxf(fmaxf(r3.x, r3.y), fmaxf(r3.z, r3.w));
            m_next = fmaxf(fmaxf(m1, m2), fmaxf(m3, m4));
        }

        // ---- insert + PAIR shift/rescale: 7 pk_mul + fixups ----
        float nv0 = mySmv * ga * ga;            // exp2(vnew - mcol)
        float rsc = frcp(fmaxf(nv0, 1.0f));     // exp2(mcol - mnew)
        float nv  = fminf(nv0, 1.0f);           // exp2(vnew - mnew)
        mcol = fmaxf(mcol, mac + flog2(mySmv)); // exact-log anchor update

        float oth = bpermf(bpa, v[7].y);        // quarter g-1's age 16g (old)
        float p7x = v[7].x;                     // own age 16g+8 (pre-shift)
        f32x2 rp = { rsc, rsc };
        #pragma unroll
        for (int k = 7; k >= 1; --k)
            v[k] = v[k - 1] * rp;               // ages +1 within quarter
        v[0].y = p7x * rsc;                     // age 16g+9 <- old 16g+8
        v[0].x = (g == 0) ? nv : oth * rsc;     // age 1 <- insert ; 16g+1 <- old 16g

        if (!even && t + 1 < T_) m_anchor = m_next;  // keep final anchor for loglik
    };

    for (int t = 0; t < T_; t += 2) {
        body(t,     0, true );
        body(t + 1, 1, false);
    }

    // ---- loglik: lds_ph[1] holds f16 exp2(alpha_{T-1} - m_anchor) ----
    if (tid < 64) {
        const _Float16* lp = lds_ph[(T_ - 1) & 1];
        float sf = (float)lp[tid] + (float)lp[tid + 64]
                 + (float)lp[tid + 128] + (float)lp[tid + 192];
        #pragma unroll
        for (int off = 1; off < 64; off <<= 1)
            sf += __shfl_xor(sf, off, 64);
        if (tid == 0) out[b] = (m_anchor + flog2(sf)) * LN2;
    }
}

extern "C" void kernel_launch(void* const* d_in, const int* in_sizes, int n_in,
                              void* d_out, int out_size, void* d_ws, size_t ws_size,
                              hipStream_t stream) {
    const float* logB = (const float*)d_in[0];   // [16,2048,256]
    const float* pi   = (const float*)d_in[1];   // [256]
    const float* A    = (const float*)d_in[2];   // [256,256]
    const float* D    = (const float*)d_in[3];   // [256,64]
    float* out = (float*)d_out;
    (void)in_sizes; (void)n_in; (void)d_ws; (void)ws_size; (void)out_size;

    hipLaunchKernelGGL(hsmm_fwd_kernel, dim3(B_), dim3(1024), 0, stream,
                       logB, pi, A, D, out);
}